// Round 3
// baseline (1063.891 us; speedup 1.0000x reference)
//
#include <hip/hip_runtime.h>
#include <math.h>

typedef const __attribute__((address_space(1))) void* gas_ptr;
typedef __attribute__((address_space(3))) void* las_ptr;

__device__ __forceinline__ void gl_lds16(const float* g, float* l) {
    // async global->LDS, 16B/lane; LDS dest = wave-uniform base + lane*16
    __builtin_amdgcn_global_load_lds((gas_ptr)g, (las_ptr)l, 16, 0, 0);
}

// ---------------------------------------------------------------------------
// K1: dots[r][k] = sum_d data[r][d] * W[k][d],  r in [0,131072)
// 64 rows/block, d-chunks of 64 floats (16 float4), double-buffered LDS via
// global_load_lds (linear dest, pre-swizzled global source col ^ (row&15)).
// Reads use the same XOR -> conflict-free b128 + wave-uniform W (scalar loads).
// ---------------------------------------------------------------------------
__global__ __launch_bounds__(256) void k_dots(const float* __restrict__ data,
                                              const float* __restrict__ W,
                                              float* __restrict__ dots) {
    __shared__ union {
        float4 ch[2][64][16];   // 32 KB: two 64-row x 64-float chunks
        float dt[64][33];       // output transpose buffer (aliases ch[0])
    } sm;
    const int tid = threadIdx.x;
    const int row0 = blockIdx.x * 64;
    const int lane = tid & 63;
    const int w = tid >> 6;
    const int k0 = __builtin_amdgcn_readfirstlane(w << 3);
    const float4* d4 = (const float4*)data;
    const float4* w4 = (const float4*)W;

#define STAGE(BUF, C)                                                          \
    {                                                                          \
        _Pragma("unroll") for (int i = 0; i < 4; ++i) {                        \
            const int rb = (w << 4) + (i << 2);                                \
            const int row = rb + (lane >> 4);                                  \
            const int cg = (lane & 15) ^ (row & 15);                           \
            gl_lds16((const float*)(d4 + (size_t)(row0 + row) * 128 +          \
                                    (C) * 16 + cg),                            \
                     (float*)&sm.ch[BUF][rb][0]);                              \
        }                                                                      \
    }

    float acc[8];
#pragma unroll
    for (int i = 0; i < 8; ++i) acc[i] = 0.f;

    STAGE(0, 0);
    __syncthreads();   // drains vmcnt before barrier

#pragma unroll
    for (int c = 0; c < 8; ++c) {
        const int cur = c & 1;
        if (c < 7) STAGE(cur ^ 1, c + 1);
#pragma unroll
        for (int dq = 0; dq < 16; ++dq) {
            float4 dv = sm.ch[cur][lane][dq ^ (lane & 15)];
#pragma unroll
            for (int kk = 0; kk < 8; ++kk) {
                float4 wv = w4[(k0 + kk) * 128 + c * 16 + dq];
                acc[kk] += dv.x * wv.x + dv.y * wv.y + dv.z * wv.z + dv.w * wv.w;
            }
        }
        __syncthreads();   // drain next-chunk loads + barrier
    }
#undef STAGE

    // transpose via LDS (aliases ch[0]; all compute done) and write coalesced
#pragma unroll
    for (int kk = 0; kk < 8; ++kk) sm.dt[lane][k0 + kk] = acc[kk];
    __syncthreads();
    float* outp = dots + (size_t)row0 * 32;
#pragma unroll
    for (int q = 0; q < 8; ++q) {
        int idx = tid + q * 256;
        outp[idx] = sm.dt[idx >> 5][idx & 31];
    }
}

// ---------------------------------------------------------------------------
// K2: per-word forward-backward, 2 waves/word (alpha || beta), scaled linear
// space. Stores Un[i]=normalize(A*gd), M[i]=unnorm beta matvec, s[i]=sum(M[i]).
// p1 ~ Un*M (normalizer Z); p2 rank-1: S += Un * (gd*M/s)^T / Z.
// dTpart = pair-hist - E .* S.
// ---------------------------------------------------------------------------
__device__ __forceinline__ float rsum32(float v) {
    v += __shfl_xor(v, 1, 32); v += __shfl_xor(v, 2, 32);
    v += __shfl_xor(v, 4, 32); v += __shfl_xor(v, 8, 32);
    v += __shfl_xor(v, 16, 32);
    return v;
}
__device__ __forceinline__ float rmax32(float v) {
    v = fmaxf(v, __shfl_xor(v, 1, 32)); v = fmaxf(v, __shfl_xor(v, 2, 32));
    v = fmaxf(v, __shfl_xor(v, 4, 32)); v = fmaxf(v, __shfl_xor(v, 8, 32));
    v = fmaxf(v, __shfl_xor(v, 16, 32));
    return v;
}

__global__ __launch_bounds__(128) void k_fwdbwd(const float* __restrict__ Tm,
                                                const int* __restrict__ labels,
                                                float* __restrict__ dp,      // in: dots, out: Pdiff
                                                float* __restrict__ dTpart) {
    __shared__ __align__(16) float gdb[2048];  // dots -> gd
    __shared__ __align__(16) float Unb[2048];
    __shared__ __align__(16) float Mb[2048];
    __shared__ float ssum[64];
    __shared__ float es[1024];
    __shared__ float Sb[1024];
    __shared__ float wtmp[32];
    __shared__ int lab[64];

    const int n = blockIdx.x;
    const int tid = threadIdx.x;
    const int wv = tid >> 6;       // 0: alpha, 1: beta
    const int lane = tid & 63;
    const int k = tid & 31;
    const int hw = tid >> 5;       // half-wave id 0..3
    float* drow = dp + (size_t)n * 2048;

    // stage dots row, zero accumulators, load labels
    {
        const float4* src = (const float4*)drow;
        float4* dst = (float4*)gdb;
#pragma unroll
        for (int i = 0; i < 4; ++i) dst[tid + i * 128] = src[tid + i * 128];
    }
#pragma unroll
    for (int i = 0; i < 8; ++i) { es[tid * 8 + i] = 0.f; Sb[tid * 8 + i] = 0.f; }
    if (tid < 64) lab[tid] = labels[n * 64 + tid];
    __syncthreads();

    // gd[i][k] = exp(dots - rowmax); 4 half-waves x 16 positions
#pragma unroll
    for (int ii = 0; ii < 16; ++ii) {
        int i = hw * 16 + ii;
        float d = gdb[i * 32 + k];
        float mx = rmax32(d);
        gdb[i * 32 + k] = __expf(d - mx);
    }
    if (tid < 63) atomicAdd(&es[lab[tid] * 32 + lab[tid + 1]], 1.0f);
    __syncthreads();

    if (wv == 0) {
        // ---- alpha forward ----
        float Ecol[32];
#pragma unroll
        for (int j = 0; j < 32; ++j) Ecol[j] = __expf(Tm[j * 32 + k]);
        float Areg = 1.f;
        for (int i = 0; i < 64; ++i) {
            float t = Areg * gdb[i * 32 + k];
            float un = t * __builtin_amdgcn_rcpf(rsum32(t));
            Unb[i * 32 + k] = un;
            asm volatile("s_waitcnt lgkmcnt(0)" ::: "memory");
            if (i < 63) {
                const float4* uv = (const float4*)(&Unb[i * 32]);
                float a = 0.f;
#pragma unroll
                for (int j8 = 0; j8 < 8; ++j8) {
                    float4 u = uv[j8];
                    a += Ecol[j8 * 4 + 0] * u.x + Ecol[j8 * 4 + 1] * u.y +
                         Ecol[j8 * 4 + 2] * u.z + Ecol[j8 * 4 + 3] * u.w;
                }
                Areg = a;
            }
        }
    } else {
        // ---- beta backward ----
        float Erow[32];
#pragma unroll
        for (int j = 0; j < 32; ++j) Erow[j] = __expf(Tm[k * 32 + j]);
        Mb[63 * 32 + k] = 1.f;
        if (lane == 0) ssum[63] = 32.f;
        float Mreg = 1.f, scur = 32.f;
        for (int i = 63; i > 0; --i) {
            float ww = gdb[i * 32 + k] * Mreg * __builtin_amdgcn_rcpf(scur);
            wtmp[k] = ww;
            asm volatile("s_waitcnt lgkmcnt(0)" ::: "memory");
            const float4* wvv = (const float4*)wtmp;
            float m2 = 0.f;
#pragma unroll
            for (int j8 = 0; j8 < 8; ++j8) {
                float4 u = wvv[j8];
                m2 += Erow[j8 * 4 + 0] * u.x + Erow[j8 * 4 + 1] * u.y +
                      Erow[j8 * 4 + 2] * u.z + Erow[j8 * 4 + 3] * u.w;
            }
            float s2 = rsum32(m2);
            Mb[(i - 1) * 32 + k] = m2;
            if (lane == 0) ssum[i - 1] = s2;
            Mreg = m2; scur = s2;
        }
    }
    __syncthreads();

    // ---- p-phase: 4 half-waves x 16 positions; fused p1 + rank-1 S ----
    float Scol[32];
#pragma unroll
    for (int j = 0; j < 32; ++j) Scol[j] = 0.f;
    const int i0 = hw * 16;
    for (int ii = 0; ii < 16; ++ii) {
        int i = i0 + ii;
        float un = Unb[i * 32 + k];
        float mm = Mb[i * 32 + k];
        float t = un * mm;
        float Z = rsum32(t);
        float rZ = __builtin_amdgcn_rcpf(Z);
        float pd = ((lab[i] == k) ? 1.f : 0.f) - t * rZ;
        drow[i * 32 + k] = pd;   // Pdiff overwrites dots
        if (i < 63) {
            float q = gdb[(i + 1) * 32 + k] * Mb[(i + 1) * 32 + k] *
                      __builtin_amdgcn_rcpf(ssum[i + 1]);
            float f = q * rZ;
            const float4* uv = (const float4*)(&Unb[i * 32]);
#pragma unroll
            for (int j8 = 0; j8 < 8; ++j8) {
                float4 u = uv[j8];
                Scol[j8 * 4 + 0] += u.x * f; Scol[j8 * 4 + 1] += u.y * f;
                Scol[j8 * 4 + 2] += u.z * f; Scol[j8 * 4 + 3] += u.w * f;
            }
        }
    }
#pragma unroll
    for (int j = 0; j < 32; ++j) atomicAdd(&Sb[j * 32 + k], Scol[j]);
    __syncthreads();

    float* op = dTpart + (size_t)n * 1024;
#pragma unroll
    for (int e = 0; e < 8; ++e) {
        int idx = tid * 8 + e;
        op[idx] = es[idx] - __expf(Tm[idx]) * Sb[idx];
    }
}

// ---------------------------------------------------------------------------
// K3: dw partials = Pdiff^T @ data. grid = 256 word-groups x 2 d-halves.
// Lane owns float4 of d (coalesced 1KB/wave); wave owns 8 k (uniform Pdiff
// loads -> scalar path). 4-row ILP keeps ~32 loads/wave in flight.
// ---------------------------------------------------------------------------
__global__ __launch_bounds__(256) void k_dw(const float* __restrict__ data,
                                            const float* __restrict__ Pd,
                                            float* __restrict__ dwp) {
    const int g = blockIdx.x >> 1;
    const int half = blockIdx.x & 1;
    const int tid = threadIdx.x;
    const int kg = __builtin_amdgcn_readfirstlane(tid >> 6);
    const int lane = tid & 63;
    const int k0 = kg << 3;
    const int d0 = half * 256 + lane * 4;

    float4 acc[8];
#pragma unroll
    for (int i = 0; i < 8; ++i) acc[i] = make_float4(0.f, 0.f, 0.f, 0.f);

    const size_t rbase = (size_t)g * 512;
    const float* dptr = data + rbase * 512 + d0;
    const float4* pptr = (const float4*)(Pd + rbase * 32) + kg * 2;

#define FMA8(PA, PB, DV)                                                       \
    acc[0].x += (PA).x * (DV).x; acc[0].y += (PA).x * (DV).y;                  \
    acc[0].z += (PA).x * (DV).z; acc[0].w += (PA).x * (DV).w;                  \
    acc[1].x += (PA).y * (DV).x; acc[1].y += (PA).y * (DV).y;                  \
    acc[1].z += (PA).y * (DV).z; acc[1].w += (PA).y * (DV).w;                  \
    acc[2].x += (PA).z * (DV).x; acc[2].y += (PA).z * (DV).y;                  \
    acc[2].z += (PA).z * (DV).z; acc[2].w += (PA).z * (DV).w;                  \
    acc[3].x += (PA).w * (DV).x; acc[3].y += (PA).w * (DV).y;                  \
    acc[3].z += (PA).w * (DV).z; acc[3].w += (PA).w * (DV).w;                  \
    acc[4].x += (PB).x * (DV).x; acc[4].y += (PB).x * (DV).y;                  \
    acc[4].z += (PB).x * (DV).z; acc[4].w += (PB).x * (DV).w;                  \
    acc[5].x += (PB).y * (DV).x; acc[5].y += (PB).y * (DV).y;                  \
    acc[5].z += (PB).y * (DV).z; acc[5].w += (PB).y * (DV).w;                  \
    acc[6].x += (PB).z * (DV).x; acc[6].y += (PB).z * (DV).y;                  \
    acc[6].z += (PB).z * (DV).z; acc[6].w += (PB).z * (DV).w;                  \
    acc[7].x += (PB).w * (DV).x; acc[7].y += (PB).w * (DV).y;                  \
    acc[7].z += (PB).w * (DV).z; acc[7].w += (PB).w * (DV).w;

    for (int r = 0; r < 512; r += 4) {
        float4 dv0 = *(const float4*)(dptr + (size_t)(r + 0) * 512);
        float4 dv1 = *(const float4*)(dptr + (size_t)(r + 1) * 512);
        float4 dv2 = *(const float4*)(dptr + (size_t)(r + 2) * 512);
        float4 dv3 = *(const float4*)(dptr + (size_t)(r + 3) * 512);
        float4 pa0 = pptr[(r + 0) * 8], pb0 = pptr[(r + 0) * 8 + 1];
        float4 pa1 = pptr[(r + 1) * 8], pb1 = pptr[(r + 1) * 8 + 1];
        float4 pa2 = pptr[(r + 2) * 8], pb2 = pptr[(r + 2) * 8 + 1];
        float4 pa3 = pptr[(r + 3) * 8], pb3 = pptr[(r + 3) * 8 + 1];
        FMA8(pa0, pb0, dv0)
        FMA8(pa1, pb1, dv1)
        FMA8(pa2, pb2, dv2)
        FMA8(pa3, pb3, dv3)
    }
#undef FMA8

    float* op = dwp + (size_t)g * 16384;
#pragma unroll
    for (int kk = 0; kk < 8; ++kk)
        *(float4*)(op + (k0 + kk) * 512 + d0) = acc[kk];
}

// ---------------------------------------------------------------------------
// K4: reduce partials, scale 1/N. blocks 0..255: dw (64 outs each);
// blocks 256..319: dT (16 outs each).
// ---------------------------------------------------------------------------
__global__ __launch_bounds__(256) void k_final(const float* __restrict__ dwp,
                                               const float* __restrict__ dTp,
                                               float* __restrict__ out) {
    __shared__ float red[256];
    const int b = blockIdx.x, t = threadIdx.x;
    const float inv = 1.0f / 2048.0f;
    if (b < 256) {
        const int q = t >> 6, ol = t & 63;
        const int oi = b * 64 + ol;
        float s = 0.f;
#pragma unroll 4
        for (int j = 0; j < 64; ++j) s += dwp[(size_t)(q * 64 + j) * 16384 + oi];
        red[t] = s;
        __syncthreads();
        if (t < 64) out[b * 64 + t] = (red[t] + red[t + 64] + red[t + 128] + red[t + 192]) * inv;
    } else {
        const int ol = t >> 4, q = t & 15;
        const int oi = (b - 256) * 16 + ol;
        float s = 0.f;
#pragma unroll 4
        for (int j = 0; j < 128; ++j) s += dTp[(size_t)(q * 128 + j) * 1024 + oi];
        s += __shfl_xor(s, 1, 16); s += __shfl_xor(s, 2, 16);
        s += __shfl_xor(s, 4, 16); s += __shfl_xor(s, 8, 16);
        if (q == 0) out[16384 + oi] = s * inv;
    }
}

// ---------------------------------------------------------------------------
// ws layout (floats): [0,4194304) dots->Pdiff | [4194304,6291456) dT partials
//                     [6291456,10485760) dw partials   (~42 MB total)
// ---------------------------------------------------------------------------
extern "C" void kernel_launch(void* const* d_in, const int* in_sizes, int n_in,
                              void* d_out, int out_size, void* d_ws, size_t ws_size,
                              hipStream_t stream) {
    const float* W = (const float*)d_in[0];
    const float* Tm = (const float*)d_in[1];
    const float* data = (const float*)d_in[2];
    const int* labels = (const int*)d_in[3];
    float* out = (float*)d_out;
    float* ws = (float*)d_ws;

    float* dots = ws;                  // 2048*64*32
    float* dTpart = ws + 4194304;      // 2048*1024
    float* dwpart = ws + 6291456;      // 256*16384

    hipLaunchKernelGGL(k_dots, dim3(2048), dim3(256), 0, stream, data, W, dots);
    hipLaunchKernelGGL(k_fwdbwd, dim3(2048), dim3(128), 0, stream, Tm, labels, dots, dTpart);
    hipLaunchKernelGGL(k_dw, dim3(512), dim3(256), 0, stream, data, dots, dwpart);
    hipLaunchKernelGGL(k_final, dim3(320), dim3(256), 0, stream, dwpart, dTpart, out);
}

// Round 4
// 426.372 us; speedup vs baseline: 2.4952x; 2.4952x over previous
//
#include <hip/hip_runtime.h>
#include <math.h>

typedef const __attribute__((address_space(1))) void* gas_ptr;
typedef __attribute__((address_space(3))) void* las_ptr;

__device__ __forceinline__ void gl_lds16(const float* g, float* l) {
    // async global->LDS, 16B/lane; LDS dest = wave-uniform base + lane*16
    __builtin_amdgcn_global_load_lds((gas_ptr)g, (las_ptr)l, 16, 0, 0);
}

// ---------------------------------------------------------------------------
// K1: dots[r][k] = sum_d data[r][d] * W[k][d],  r in [0,131072)
// 64 rows/block, d-chunks of 64 floats (16 float4), double-buffered LDS via
// global_load_lds (linear dest, pre-swizzled global source col ^ (row&15)).
// Reads use the same XOR -> conflict-free b128 + wave-uniform W (scalar loads).
// NOTE: chunk loop MUST stay rolled (unroll 1) — full unroll spills (r3: 256
// VGPR, 400 MB scratch writes, 880 us).
// ---------------------------------------------------------------------------
__global__ __launch_bounds__(256, 2) void k_dots(const float* __restrict__ data,
                                                 const float* __restrict__ W,
                                                 float* __restrict__ dots) {
    __shared__ union {
        float4 ch[2][64][16];   // 32 KB: two 64-row x 64-float chunks
        float dt[64][33];       // output transpose buffer (aliases ch[0])
    } sm;
    const int tid = threadIdx.x;
    const int row0 = blockIdx.x * 64;
    const int lane = tid & 63;
    const int w = tid >> 6;
    const int k0 = __builtin_amdgcn_readfirstlane(w << 3);
    const float4* d4 = (const float4*)data;
    const float4* w4 = (const float4*)W;

#define STAGE(BUF, C)                                                          \
    {                                                                          \
        _Pragma("unroll") for (int i = 0; i < 4; ++i) {                        \
            const int rb = (w << 4) + (i << 2);                                \
            const int row = rb + (lane >> 4);                                  \
            const int cg = (lane & 15) ^ (row & 15);                           \
            gl_lds16((const float*)(d4 + (size_t)(row0 + row) * 128 +          \
                                    (C) * 16 + cg),                            \
                     (float*)&sm.ch[BUF][rb][0]);                              \
        }                                                                      \
    }

    float acc[8];
#pragma unroll
    for (int i = 0; i < 8; ++i) acc[i] = 0.f;

    STAGE(0, 0);
    __syncthreads();   // drains vmcnt before barrier

#pragma unroll 1
    for (int c = 0; c < 8; ++c) {
        const int cur = c & 1;
        if (c < 7) STAGE(cur ^ 1, c + 1);
#pragma unroll
        for (int dq = 0; dq < 16; ++dq) {
            float4 dv = sm.ch[cur][lane][dq ^ (lane & 15)];
#pragma unroll
            for (int kk = 0; kk < 8; ++kk) {
                float4 wv = w4[(k0 + kk) * 128 + c * 16 + dq];
                acc[kk] += dv.x * wv.x + dv.y * wv.y + dv.z * wv.z + dv.w * wv.w;
            }
        }
        __syncthreads();   // drain next-chunk loads + barrier
    }
#undef STAGE

    // transpose via LDS (aliases ch[0]; all compute done) and write coalesced
#pragma unroll
    for (int kk = 0; kk < 8; ++kk) sm.dt[lane][k0 + kk] = acc[kk];
    __syncthreads();
    float* outp = dots + (size_t)row0 * 32;
#pragma unroll
    for (int q = 0; q < 8; ++q) {
        int idx = tid + q * 256;
        outp[idx] = sm.dt[idx >> 5][idx & 31];
    }
}

// ---------------------------------------------------------------------------
// K2: per-word forward-backward, 2 waves/word (alpha || beta), scaled linear
// space. Stores Un[i]=normalize(A*gd), M[i]=unnorm beta matvec, s[i]=sum(M[i]).
// p1 ~ Un*M (normalizer Z); p2 rank-1: S += Un * (gd*M/s)^T / Z.
// dTpart = pair-hist (global atomics) - E .* S.
// ---------------------------------------------------------------------------
__device__ __forceinline__ float rsum32(float v) {
    v += __shfl_xor(v, 1, 32); v += __shfl_xor(v, 2, 32);
    v += __shfl_xor(v, 4, 32); v += __shfl_xor(v, 8, 32);
    v += __shfl_xor(v, 16, 32);
    return v;
}
__device__ __forceinline__ float rmax32(float v) {
    v = fmaxf(v, __shfl_xor(v, 1, 32)); v = fmaxf(v, __shfl_xor(v, 2, 32));
    v = fmaxf(v, __shfl_xor(v, 4, 32)); v = fmaxf(v, __shfl_xor(v, 8, 32));
    v = fmaxf(v, __shfl_xor(v, 16, 32));
    return v;
}

__global__ __launch_bounds__(128) void k_fwdbwd(const float* __restrict__ Tm,
                                                const int* __restrict__ labels,
                                                float* __restrict__ dp,      // in: dots, out: Pdiff
                                                float* __restrict__ dTpart) {
    __shared__ __align__(16) float gdb[2048];  // dots -> gd
    __shared__ __align__(16) float Unb[2048];
    __shared__ __align__(16) float Mb[2048];
    __shared__ float ssum[64];
    __shared__ float Sb[1024];
    __shared__ float wtmp[32];
    __shared__ int lab[64];

    const int n = blockIdx.x;
    const int tid = threadIdx.x;
    const int wv = tid >> 6;       // 0: alpha, 1: beta
    const int lane = tid & 63;
    const int k = tid & 31;
    const int hw = tid >> 5;       // half-wave id 0..3
    float* drow = dp + (size_t)n * 2048;

    // stage dots row, zero accumulators, load labels
    {
        const float4* src = (const float4*)drow;
        float4* dst = (float4*)gdb;
#pragma unroll
        for (int i = 0; i < 4; ++i) dst[tid + i * 128] = src[tid + i * 128];
    }
#pragma unroll
    for (int i = 0; i < 8; ++i) Sb[tid * 8 + i] = 0.f;
    if (tid < 64) lab[tid] = labels[n * 64 + tid];
    __syncthreads();

    // gd[i][k] = exp(dots - rowmax); 4 half-waves x 16 positions
#pragma unroll
    for (int ii = 0; ii < 16; ++ii) {
        int i = hw * 16 + ii;
        float d = gdb[i * 32 + k];
        float mx = rmax32(d);
        gdb[i * 32 + k] = __expf(d - mx);
    }
    __syncthreads();

    if (wv == 0) {
        // ---- alpha forward ----
        float Ecol[32];
#pragma unroll
        for (int j = 0; j < 32; ++j) Ecol[j] = __expf(Tm[j * 32 + k]);
        float Areg = 1.f;
        for (int i = 0; i < 64; ++i) {
            float t = Areg * gdb[i * 32 + k];
            float un = t * __builtin_amdgcn_rcpf(rsum32(t));
            Unb[i * 32 + k] = un;
            asm volatile("s_waitcnt lgkmcnt(0)" ::: "memory");
            if (i < 63) {
                const float4* uv = (const float4*)(&Unb[i * 32]);
                float a = 0.f;
#pragma unroll
                for (int j8 = 0; j8 < 8; ++j8) {
                    float4 u = uv[j8];
                    a += Ecol[j8 * 4 + 0] * u.x + Ecol[j8 * 4 + 1] * u.y +
                         Ecol[j8 * 4 + 2] * u.z + Ecol[j8 * 4 + 3] * u.w;
                }
                Areg = a;
            }
        }
    } else {
        // ---- beta backward ----
        float Erow[32];
#pragma unroll
        for (int j = 0; j < 32; ++j) Erow[j] = __expf(Tm[k * 32 + j]);
        Mb[63 * 32 + k] = 1.f;
        if (lane == 0) ssum[63] = 32.f;
        float Mreg = 1.f, scur = 32.f;
        for (int i = 63; i > 0; --i) {
            float ww = gdb[i * 32 + k] * Mreg * __builtin_amdgcn_rcpf(scur);
            wtmp[k] = ww;
            asm volatile("s_waitcnt lgkmcnt(0)" ::: "memory");
            const float4* wvv = (const float4*)wtmp;
            float m2 = 0.f;
#pragma unroll
            for (int j8 = 0; j8 < 8; ++j8) {
                float4 u = wvv[j8];
                m2 += Erow[j8 * 4 + 0] * u.x + Erow[j8 * 4 + 1] * u.y +
                      Erow[j8 * 4 + 2] * u.z + Erow[j8 * 4 + 3] * u.w;
            }
            float s2 = rsum32(m2);
            Mb[(i - 1) * 32 + k] = m2;
            if (lane == 0) ssum[i - 1] = s2;
            Mreg = m2; scur = s2;
        }
    }
    __syncthreads();

    // ---- p-phase: 4 half-waves x 16 positions; fused p1 + rank-1 S ----
    float Scol[32];
#pragma unroll
    for (int j = 0; j < 32; ++j) Scol[j] = 0.f;
    const int i0 = hw * 16;
    for (int ii = 0; ii < 16; ++ii) {
        int i = i0 + ii;
        float un = Unb[i * 32 + k];
        float mm = Mb[i * 32 + k];
        float t = un * mm;
        float Z = rsum32(t);
        float rZ = __builtin_amdgcn_rcpf(Z);
        float pd = ((lab[i] == k) ? 1.f : 0.f) - t * rZ;
        drow[i * 32 + k] = pd;   // Pdiff overwrites dots
        if (i < 63) {
            float q = gdb[(i + 1) * 32 + k] * Mb[(i + 1) * 32 + k] *
                      __builtin_amdgcn_rcpf(ssum[i + 1]);
            float f = q * rZ;
            const float4* uv = (const float4*)(&Unb[i * 32]);
#pragma unroll
            for (int j8 = 0; j8 < 8; ++j8) {
                float4 u = uv[j8];
                Scol[j8 * 4 + 0] += u.x * f; Scol[j8 * 4 + 1] += u.y * f;
                Scol[j8 * 4 + 2] += u.z * f; Scol[j8 * 4 + 3] += u.w * f;
            }
        }
    }
#pragma unroll
    for (int j = 0; j < 32; ++j) atomicAdd(&Sb[j * 32 + k], Scol[j]);
    __syncthreads();

    float* op = dTpart + (size_t)n * 1024;
#pragma unroll
    for (int e = 0; e < 8; ++e) {
        int idx = tid * 8 + e;
        op[idx] = -__expf(Tm[idx]) * Sb[idx];
    }
    __syncthreads();
    // pair-label histogram straight into dTpart (ordered after stores above)
    if (tid < 63) atomicAdd(&op[lab[tid] * 32 + lab[tid + 1]], 1.0f);
}

// ---------------------------------------------------------------------------
// K3: dw partials = Pdiff^T @ data. grid = 256 word-groups x 2 d-halves.
// Lane owns float4 of d (coalesced 1KB/wave); wave owns 8 k (uniform Pdiff
// loads -> scalar path). 4-row ILP keeps ~32 loads/wave in flight.
// ---------------------------------------------------------------------------
__global__ __launch_bounds__(256) void k_dw(const float* __restrict__ data,
                                            const float* __restrict__ Pd,
                                            float* __restrict__ dwp) {
    const int g = blockIdx.x >> 1;
    const int half = blockIdx.x & 1;
    const int tid = threadIdx.x;
    const int kg = __builtin_amdgcn_readfirstlane(tid >> 6);
    const int lane = tid & 63;
    const int k0 = kg << 3;
    const int d0 = half * 256 + lane * 4;

    float4 acc[8];
#pragma unroll
    for (int i = 0; i < 8; ++i) acc[i] = make_float4(0.f, 0.f, 0.f, 0.f);

    const size_t rbase = (size_t)g * 512;
    const float* dptr = data + rbase * 512 + d0;
    const float4* pptr = (const float4*)(Pd + rbase * 32) + kg * 2;

#define FMA8(PA, PB, DV)                                                       \
    acc[0].x += (PA).x * (DV).x; acc[0].y += (PA).x * (DV).y;                  \
    acc[0].z += (PA).x * (DV).z; acc[0].w += (PA).x * (DV).w;                  \
    acc[1].x += (PA).y * (DV).x; acc[1].y += (PA).y * (DV).y;                  \
    acc[1].z += (PA).y * (DV).z; acc[1].w += (PA).y * (DV).w;                  \
    acc[2].x += (PA).z * (DV).x; acc[2].y += (PA).z * (DV).y;                  \
    acc[2].z += (PA).z * (DV).z; acc[2].w += (PA).z * (DV).w;                  \
    acc[3].x += (PA).w * (DV).x; acc[3].y += (PA).w * (DV).y;                  \
    acc[3].z += (PA).w * (DV).z; acc[3].w += (PA).w * (DV).w;                  \
    acc[4].x += (PB).x * (DV).x; acc[4].y += (PB).x * (DV).y;                  \
    acc[4].z += (PB).x * (DV).z; acc[4].w += (PB).x * (DV).w;                  \
    acc[5].x += (PB).y * (DV).x; acc[5].y += (PB).y * (DV).y;                  \
    acc[5].z += (PB).y * (DV).z; acc[5].w += (PB).y * (DV).w;                  \
    acc[6].x += (PB).z * (DV).x; acc[6].y += (PB).z * (DV).y;                  \
    acc[6].z += (PB).z * (DV).z; acc[6].w += (PB).z * (DV).w;                  \
    acc[7].x += (PB).w * (DV).x; acc[7].y += (PB).w * (DV).y;                  \
    acc[7].z += (PB).w * (DV).z; acc[7].w += (PB).w * (DV).w;

    for (int r = 0; r < 512; r += 4) {
        float4 dv0 = *(const float4*)(dptr + (size_t)(r + 0) * 512);
        float4 dv1 = *(const float4*)(dptr + (size_t)(r + 1) * 512);
        float4 dv2 = *(const float4*)(dptr + (size_t)(r + 2) * 512);
        float4 dv3 = *(const float4*)(dptr + (size_t)(r + 3) * 512);
        float4 pa0 = pptr[(r + 0) * 8], pb0 = pptr[(r + 0) * 8 + 1];
        float4 pa1 = pptr[(r + 1) * 8], pb1 = pptr[(r + 1) * 8 + 1];
        float4 pa2 = pptr[(r + 2) * 8], pb2 = pptr[(r + 2) * 8 + 1];
        float4 pa3 = pptr[(r + 3) * 8], pb3 = pptr[(r + 3) * 8 + 1];
        FMA8(pa0, pb0, dv0)
        FMA8(pa1, pb1, dv1)
        FMA8(pa2, pb2, dv2)
        FMA8(pa3, pb3, dv3)
    }
#undef FMA8

    float* op = dwp + (size_t)g * 16384;
#pragma unroll
    for (int kk = 0; kk < 8; ++kk)
        *(float4*)(op + (k0 + kk) * 512 + d0) = acc[kk];
}

// ---------------------------------------------------------------------------
// K4: reduce partials, scale 1/N. blocks 0..255: dw (64 outs each);
// blocks 256..319: dT (16 outs each).
// ---------------------------------------------------------------------------
__global__ __launch_bounds__(256) void k_final(const float* __restrict__ dwp,
                                               const float* __restrict__ dTp,
                                               float* __restrict__ out) {
    __shared__ float red[256];
    const int b = blockIdx.x, t = threadIdx.x;
    const float inv = 1.0f / 2048.0f;
    if (b < 256) {
        const int q = t >> 6, ol = t & 63;
        const int oi = b * 64 + ol;
        float s = 0.f;
#pragma unroll 4
        for (int j = 0; j < 64; ++j) s += dwp[(size_t)(q * 64 + j) * 16384 + oi];
        red[t] = s;
        __syncthreads();
        if (t < 64) out[b * 64 + t] = (red[t] + red[t + 64] + red[t + 128] + red[t + 192]) * inv;
    } else {
        const int ol = t >> 4, q = t & 15;
        const int oi = (b - 256) * 16 + ol;
        float s = 0.f;
#pragma unroll 4
        for (int j = 0; j < 128; ++j) s += dTp[(size_t)(q * 128 + j) * 1024 + oi];
        s += __shfl_xor(s, 1, 16); s += __shfl_xor(s, 2, 16);
        s += __shfl_xor(s, 4, 16); s += __shfl_xor(s, 8, 16);
        if (q == 0) out[16384 + oi] = s * inv;
    }
}

// ---------------------------------------------------------------------------
// ws layout (floats): [0,4194304) dots->Pdiff | [4194304,6291456) dT partials
//                     [6291456,10485760) dw partials   (~42 MB total)
// ---------------------------------------------------------------------------
extern "C" void kernel_launch(void* const* d_in, const int* in_sizes, int n_in,
                              void* d_out, int out_size, void* d_ws, size_t ws_size,
                              hipStream_t stream) {
    const float* W = (const float*)d_in[0];
    const float* Tm = (const float*)d_in[1];
    const float* data = (const float*)d_in[2];
    const int* labels = (const int*)d_in[3];
    float* out = (float*)d_out;
    float* ws = (float*)d_ws;

    float* dots = ws;                  // 2048*64*32
    float* dTpart = ws + 4194304;      // 2048*1024
    float* dwpart = ws + 6291456;      // 256*16384

    hipLaunchKernelGGL(k_dots, dim3(2048), dim3(256), 0, stream, data, W, dots);
    hipLaunchKernelGGL(k_fwdbwd, dim3(2048), dim3(128), 0, stream, Tm, labels, dots, dTpart);
    hipLaunchKernelGGL(k_dw, dim3(512), dim3(256), 0, stream, data, dots, dwpart);
    hipLaunchKernelGGL(k_final, dim3(320), dim3(256), 0, stream, dwpart, dTpart, out);
}

// Round 5
// 297.735 us; speedup vs baseline: 3.5733x; 1.4321x over previous
//
#include <hip/hip_runtime.h>
#include <math.h>

typedef __bf16 bf16x8 __attribute__((ext_vector_type(8)));
typedef float f32x4 __attribute__((ext_vector_type(4)));

__device__ __forceinline__ bf16x8 to_bf16x8(float4 a, float4 b) {
    bf16x8 r;
    r[0] = (__bf16)a.x; r[1] = (__bf16)a.y; r[2] = (__bf16)a.z; r[3] = (__bf16)a.w;
    r[4] = (__bf16)b.x; r[5] = (__bf16)b.y; r[6] = (__bf16)b.z; r[7] = (__bf16)b.w;
    return r;
}
#define MFMA16(A, B, C) __builtin_amdgcn_mfma_f32_16x16x32_bf16((A), (B), (C), 0, 0, 0)

// ---------------------------------------------------------------------------
// K1 (MFMA): dots[r][k] = sum_d data[r][d] * W[k][d]  == C = A @ B^T, B^T = W.
// Layout per m89/m91 (HW-verified gemm_bt): a-frag lane l holds
// A[l&15][(l>>4)*8+j]; b-frag identical from W rows; C: col=lane&15,
// row=(lane>>4)*4+reg. Block = 4 waves x 32 rows = 128 rows; grid 1024.
// fp32 loads, on-the-fly bf16 convert (v_cvt_pk_bf16_f32), no LDS.
// ---------------------------------------------------------------------------
__global__ __launch_bounds__(256, 4) void k_dots(const float* __restrict__ data,
                                                 const float* __restrict__ W,
                                                 float* __restrict__ dots) {
    const int tid = threadIdx.x;
    const int w = __builtin_amdgcn_readfirstlane(tid >> 6);
    const int l = tid & 63;
    const int m16 = l & 15;         // A-row / B-row within tile
    const int kb = l >> 4;          // k-block (8 elems each)
    const size_t row0 = (size_t)blockIdx.x * 128 + w * 32;

    const float* arow0 = data + (row0 + m16) * 512 + kb * 8;
    const float* arow1 = arow0 + 16 * 512;
    const float* brow0 = W + (size_t)m16 * 512 + kb * 8;   // labels 0..15
    const float* brow1 = brow0 + 16 * 512;                  // labels 16..31

    f32x4 acc00 = {0.f, 0.f, 0.f, 0.f}, acc01 = {0.f, 0.f, 0.f, 0.f};
    f32x4 acc10 = {0.f, 0.f, 0.f, 0.f}, acc11 = {0.f, 0.f, 0.f, 0.f};

#pragma unroll 1
    for (int kk = 0; kk < 16; ++kk) {
        const int off = kk * 32;
        float4 a0l = *(const float4*)(arow0 + off);
        float4 a0h = *(const float4*)(arow0 + off + 4);
        float4 a1l = *(const float4*)(arow1 + off);
        float4 a1h = *(const float4*)(arow1 + off + 4);
        float4 b0l = *(const float4*)(brow0 + off);
        float4 b0h = *(const float4*)(brow0 + off + 4);
        float4 b1l = *(const float4*)(brow1 + off);
        float4 b1h = *(const float4*)(brow1 + off + 4);
        bf16x8 a0 = to_bf16x8(a0l, a0h), a1 = to_bf16x8(a1l, a1h);
        bf16x8 b0 = to_bf16x8(b0l, b0h), b1 = to_bf16x8(b1l, b1h);
        acc00 = MFMA16(a0, b0, acc00);
        acc01 = MFMA16(a0, b1, acc01);
        acc10 = MFMA16(a1, b0, acc10);
        acc11 = MFMA16(a1, b1, acc11);
    }

    // C-write: row = tile*16 + kb*4 + r, col = u*16 + m16
    float* ob = dots + (row0 + kb * 4) * 32 + m16;
#pragma unroll
    for (int r = 0; r < 4; ++r) {
        ob[r * 32]       = acc00[r];
        ob[r * 32 + 16]  = acc01[r];
        ob[512 + r * 32]      = acc10[r];   // +16 rows
        ob[512 + r * 32 + 16] = acc11[r];
    }
}

// ---------------------------------------------------------------------------
// K2: per-word forward-backward, 2 waves/word (alpha || beta), scaled linear
// space. Stores Un[i]=normalize(A*gd), M[i]=unnorm beta matvec, s[i]=sum(M[i]).
// p1 ~ Un*M (normalizer Z); p2 rank-1: S += Un * (gd*M/s)^T / Z.
// dTpart = pair-hist (global atomics) - E .* S.
// ---------------------------------------------------------------------------
__device__ __forceinline__ float rsum32(float v) {
    v += __shfl_xor(v, 1, 32); v += __shfl_xor(v, 2, 32);
    v += __shfl_xor(v, 4, 32); v += __shfl_xor(v, 8, 32);
    v += __shfl_xor(v, 16, 32);
    return v;
}
__device__ __forceinline__ float rmax32(float v) {
    v = fmaxf(v, __shfl_xor(v, 1, 32)); v = fmaxf(v, __shfl_xor(v, 2, 32));
    v = fmaxf(v, __shfl_xor(v, 4, 32)); v = fmaxf(v, __shfl_xor(v, 8, 32));
    v = fmaxf(v, __shfl_xor(v, 16, 32));
    return v;
}

__global__ __launch_bounds__(128) void k_fwdbwd(const float* __restrict__ Tm,
                                                const int* __restrict__ labels,
                                                float* __restrict__ dp,      // in: dots, out: Pdiff
                                                float* __restrict__ dTpart) {
    __shared__ __align__(16) float gdb[2048];  // dots -> gd
    __shared__ __align__(16) float Unb[2048];
    __shared__ __align__(16) float Mb[2048];
    __shared__ float ssum[64];
    __shared__ float Sb[1024];
    __shared__ float wtmp[32];
    __shared__ int lab[64];

    const int n = blockIdx.x;
    const int tid = threadIdx.x;
    const int wv = tid >> 6;       // 0: alpha, 1: beta
    const int lane = tid & 63;
    const int k = tid & 31;
    const int hw = tid >> 5;       // half-wave id 0..3
    float* drow = dp + (size_t)n * 2048;

    // stage dots row, zero accumulators, load labels
    {
        const float4* src = (const float4*)drow;
        float4* dst = (float4*)gdb;
#pragma unroll
        for (int i = 0; i < 4; ++i) dst[tid + i * 128] = src[tid + i * 128];
    }
#pragma unroll
    for (int i = 0; i < 8; ++i) Sb[tid * 8 + i] = 0.f;
    if (tid < 64) lab[tid] = labels[n * 64 + tid];
    __syncthreads();

    // gd[i][k] = exp(dots - rowmax); 4 half-waves x 16 positions
#pragma unroll
    for (int ii = 0; ii < 16; ++ii) {
        int i = hw * 16 + ii;
        float d = gdb[i * 32 + k];
        float mx = rmax32(d);
        gdb[i * 32 + k] = __expf(d - mx);
    }
    __syncthreads();

    if (wv == 0) {
        // ---- alpha forward ----
        float Ecol[32];
#pragma unroll
        for (int j = 0; j < 32; ++j) Ecol[j] = __expf(Tm[j * 32 + k]);
        float Areg = 1.f;
        for (int i = 0; i < 64; ++i) {
            float t = Areg * gdb[i * 32 + k];
            float un = t * __builtin_amdgcn_rcpf(rsum32(t));
            Unb[i * 32 + k] = un;
            asm volatile("s_waitcnt lgkmcnt(0)" ::: "memory");
            if (i < 63) {
                const float4* uv = (const float4*)(&Unb[i * 32]);
                float a = 0.f;
#pragma unroll
                for (int j8 = 0; j8 < 8; ++j8) {
                    float4 u = uv[j8];
                    a += Ecol[j8 * 4 + 0] * u.x + Ecol[j8 * 4 + 1] * u.y +
                         Ecol[j8 * 4 + 2] * u.z + Ecol[j8 * 4 + 3] * u.w;
                }
                Areg = a;
            }
        }
    } else {
        // ---- beta backward ----
        float Erow[32];
#pragma unroll
        for (int j = 0; j < 32; ++j) Erow[j] = __expf(Tm[k * 32 + j]);
        Mb[63 * 32 + k] = 1.f;
        if (lane == 0) ssum[63] = 32.f;
        float Mreg = 1.f, scur = 32.f;
        for (int i = 63; i > 0; --i) {
            float ww = gdb[i * 32 + k] * Mreg * __builtin_amdgcn_rcpf(scur);
            wtmp[k] = ww;
            asm volatile("s_waitcnt lgkmcnt(0)" ::: "memory");
            const float4* wvv = (const float4*)wtmp;
            float m2 = 0.f;
#pragma unroll
            for (int j8 = 0; j8 < 8; ++j8) {
                float4 u = wvv[j8];
                m2 += Erow[j8 * 4 + 0] * u.x + Erow[j8 * 4 + 1] * u.y +
                      Erow[j8 * 4 + 2] * u.z + Erow[j8 * 4 + 3] * u.w;
            }
            float s2 = rsum32(m2);
            Mb[(i - 1) * 32 + k] = m2;
            if (lane == 0) ssum[i - 1] = s2;
            Mreg = m2; scur = s2;
        }
    }
    __syncthreads();

    // ---- p-phase: 4 half-waves x 16 positions; fused p1 + rank-1 S ----
    float Scol[32];
#pragma unroll
    for (int j = 0; j < 32; ++j) Scol[j] = 0.f;
    const int i0 = hw * 16;
    for (int ii = 0; ii < 16; ++ii) {
        int i = i0 + ii;
        float un = Unb[i * 32 + k];
        float mm = Mb[i * 32 + k];
        float t = un * mm;
        float Z = rsum32(t);
        float rZ = __builtin_amdgcn_rcpf(Z);
        float pd = ((lab[i] == k) ? 1.f : 0.f) - t * rZ;
        drow[i * 32 + k] = pd;   // Pdiff overwrites dots
        if (i < 63) {
            float q = gdb[(i + 1) * 32 + k] * Mb[(i + 1) * 32 + k] *
                      __builtin_amdgcn_rcpf(ssum[i + 1]);
            float f = q * rZ;
            const float4* uv = (const float4*)(&Unb[i * 32]);
#pragma unroll
            for (int j8 = 0; j8 < 8; ++j8) {
                float4 u = uv[j8];
                Scol[j8 * 4 + 0] += u.x * f; Scol[j8 * 4 + 1] += u.y * f;
                Scol[j8 * 4 + 2] += u.z * f; Scol[j8 * 4 + 3] += u.w * f;
            }
        }
    }
#pragma unroll
    for (int j = 0; j < 32; ++j) atomicAdd(&Sb[j * 32 + k], Scol[j]);
    __syncthreads();

    float* op = dTpart + (size_t)n * 1024;
#pragma unroll
    for (int e = 0; e < 8; ++e) {
        int idx = tid * 8 + e;
        op[idx] = -__expf(Tm[idx]) * Sb[idx];
    }
    __syncthreads();
    // pair-label histogram straight into dTpart (ordered after stores above)
    if (tid < 63) atomicAdd(&op[lab[tid] * 32 + lab[tid + 1]], 1.0f);
}

// ---------------------------------------------------------------------------
// K3: dw partials = Pdiff^T @ data. grid = 256 word-groups x 4 d-quarters
// (1024 blocks -> 4 blocks/CU, 16 waves/CU). Lane owns float2 of d (8 B,
// 512 B/wave coalesced); wave owns 8 k (uniform Pdiff -> scalar path).
// 4-row ILP for in-flight loads.
// ---------------------------------------------------------------------------
__global__ __launch_bounds__(256) void k_dw(const float* __restrict__ data,
                                            const float* __restrict__ Pd,
                                            float* __restrict__ dwp) {
    const int g = blockIdx.x >> 2;
    const int q = blockIdx.x & 3;
    const int tid = threadIdx.x;
    const int kg = __builtin_amdgcn_readfirstlane(tid >> 6);
    const int lane = tid & 63;
    const int k0 = kg << 3;
    const int d0 = q * 128 + lane * 2;

    float2 acc[8];
#pragma unroll
    for (int i = 0; i < 8; ++i) acc[i] = make_float2(0.f, 0.f);

    const size_t rbase = (size_t)g * 512;
    const float* dptr = data + rbase * 512 + d0;
    const float4* pptr = (const float4*)(Pd + rbase * 32) + kg * 2;

#define FMA8_2(PA, PB, DV)                                                     \
    acc[0].x += (PA).x * (DV).x; acc[0].y += (PA).x * (DV).y;                  \
    acc[1].x += (PA).y * (DV).x; acc[1].y += (PA).y * (DV).y;                  \
    acc[2].x += (PA).z * (DV).x; acc[2].y += (PA).z * (DV).y;                  \
    acc[3].x += (PA).w * (DV).x; acc[3].y += (PA).w * (DV).y;                  \
    acc[4].x += (PB).x * (DV).x; acc[4].y += (PB).x * (DV).y;                  \
    acc[5].x += (PB).y * (DV).x; acc[5].y += (PB).y * (DV).y;                  \
    acc[6].x += (PB).z * (DV).x; acc[6].y += (PB).z * (DV).y;                  \
    acc[7].x += (PB).w * (DV).x; acc[7].y += (PB).w * (DV).y;

    for (int r = 0; r < 512; r += 4) {
        float2 dv0 = *(const float2*)(dptr + (size_t)(r + 0) * 512);
        float2 dv1 = *(const float2*)(dptr + (size_t)(r + 1) * 512);
        float2 dv2 = *(const float2*)(dptr + (size_t)(r + 2) * 512);
        float2 dv3 = *(const float2*)(dptr + (size_t)(r + 3) * 512);
        float4 pa0 = pptr[(r + 0) * 8], pb0 = pptr[(r + 0) * 8 + 1];
        float4 pa1 = pptr[(r + 1) * 8], pb1 = pptr[(r + 1) * 8 + 1];
        float4 pa2 = pptr[(r + 2) * 8], pb2 = pptr[(r + 2) * 8 + 1];
        float4 pa3 = pptr[(r + 3) * 8], pb3 = pptr[(r + 3) * 8 + 1];
        FMA8_2(pa0, pb0, dv0)
        FMA8_2(pa1, pb1, dv1)
        FMA8_2(pa2, pb2, dv2)
        FMA8_2(pa3, pb3, dv3)
    }
#undef FMA8_2

    float* op = dwp + (size_t)g * 16384;
#pragma unroll
    for (int kk = 0; kk < 8; ++kk)
        *(float2*)(op + (k0 + kk) * 512 + d0) = acc[kk];
}

// ---------------------------------------------------------------------------
// K4: reduce partials, scale 1/N. blocks 0..255: dw (64 outs each);
// blocks 256..319: dT (16 outs each).
// ---------------------------------------------------------------------------
__global__ __launch_bounds__(256) void k_final(const float* __restrict__ dwp,
                                               const float* __restrict__ dTp,
                                               float* __restrict__ out) {
    __shared__ float red[256];
    const int b = blockIdx.x, t = threadIdx.x;
    const float inv = 1.0f / 2048.0f;
    if (b < 256) {
        const int q = t >> 6, ol = t & 63;
        const int oi = b * 64 + ol;
        float s = 0.f;
#pragma unroll 4
        for (int j = 0; j < 64; ++j) s += dwp[(size_t)(q * 64 + j) * 16384 + oi];
        red[t] = s;
        __syncthreads();
        if (t < 64) out[b * 64 + t] = (red[t] + red[t + 64] + red[t + 128] + red[t + 192]) * inv;
    } else {
        const int ol = t >> 4, q = t & 15;
        const int oi = (b - 256) * 16 + ol;
        float s = 0.f;
#pragma unroll 4
        for (int j = 0; j < 128; ++j) s += dTp[(size_t)(q * 128 + j) * 1024 + oi];
        s += __shfl_xor(s, 1, 16); s += __shfl_xor(s, 2, 16);
        s += __shfl_xor(s, 4, 16); s += __shfl_xor(s, 8, 16);
        if (q == 0) out[16384 + oi] = s * inv;
    }
}

// ---------------------------------------------------------------------------
// ws layout (floats): [0,4194304) dots->Pdiff | [4194304,6291456) dT partials
//                     [6291456,10485760) dw partials   (~42 MB total)
// ---------------------------------------------------------------------------
extern "C" void kernel_launch(void* const* d_in, const int* in_sizes, int n_in,
                              void* d_out, int out_size, void* d_ws, size_t ws_size,
                              hipStream_t stream) {
    const float* W = (const float*)d_in[0];
    const float* Tm = (const float*)d_in[1];
    const float* data = (const float*)d_in[2];
    const int* labels = (const int*)d_in[3];
    float* out = (float*)d_out;
    float* ws = (float*)d_ws;

    float* dots = ws;                  // 2048*64*32
    float* dTpart = ws + 4194304;      // 2048*1024
    float* dwpart = ws + 6291456;      // 256*16384

    hipLaunchKernelGGL(k_dots, dim3(1024), dim3(256), 0, stream, data, W, dots);
    hipLaunchKernelGGL(k_fwdbwd, dim3(2048), dim3(128), 0, stream, Tm, labels, dots, dTpart);
    hipLaunchKernelGGL(k_dw, dim3(1024), dim3(256), 0, stream, data, dots, dwpart);
    hipLaunchKernelGGL(k_final, dim3(320), dim3(256), 0, stream, dwpart, dTpart, out);
}

// Round 6
// 278.847 us; speedup vs baseline: 3.8153x; 1.0677x over previous
//
#include <hip/hip_runtime.h>
#include <math.h>

typedef __bf16 bf16x8 __attribute__((ext_vector_type(8)));
typedef float f32x4 __attribute__((ext_vector_type(4)));

__device__ __forceinline__ bf16x8 to_bf16x8(float4 a, float4 b) {
    bf16x8 r;
    r[0] = (__bf16)a.x; r[1] = (__bf16)a.y; r[2] = (__bf16)a.z; r[3] = (__bf16)a.w;
    r[4] = (__bf16)b.x; r[5] = (__bf16)b.y; r[6] = (__bf16)b.z; r[7] = (__bf16)b.w;
    return r;
}
#define MFMA16(A, B, C) __builtin_amdgcn_mfma_f32_16x16x32_bf16((A), (B), (C), 0, 0, 0)

__device__ __forceinline__ float rsum32(float v) {
    v += __shfl_xor(v, 1, 32); v += __shfl_xor(v, 2, 32);
    v += __shfl_xor(v, 4, 32); v += __shfl_xor(v, 8, 32);
    v += __shfl_xor(v, 16, 32);
    return v;
}
__device__ __forceinline__ float rmax32(float v) {
    v = fmaxf(v, __shfl_xor(v, 1, 32)); v = fmaxf(v, __shfl_xor(v, 2, 32));
    v = fmaxf(v, __shfl_xor(v, 4, 32)); v = fmaxf(v, __shfl_xor(v, 8, 32));
    v = fmaxf(v, __shfl_xor(v, 16, 32));
    return v;
}

// ---------------------------------------------------------------------------
// k_word: fused per-word pipeline. Block = 1 word, 128 threads (2 waves).
// Phase A (MFMA): dots[64][32] = data_word @ W^T straight into LDS (layout
//   per m89/m91 gemm_bt, identical to the pass-verified r4/r5 k_dots).
// Phase B: gd = exp(dots - rowmax).
// Phase C: alpha (wave0) || beta (wave1) scaled linear-space recursions.
// Phase D: p-phase -> Pdiff (to ws for k_dw) + rank-1 S accumulation.
// dTpart = pair-hist (atomics into own row) - E .* S.
// ---------------------------------------------------------------------------
__global__ __launch_bounds__(128) void k_word(const float* __restrict__ data,
                                              const float* __restrict__ W,
                                              const float* __restrict__ Tm,
                                              const int* __restrict__ labels,
                                              float* __restrict__ Pdiff,
                                              float* __restrict__ dTpart) {
    __shared__ __align__(16) float gdb[2048];  // raw dots -> gd
    __shared__ __align__(16) float Unb[2048];
    __shared__ __align__(16) float Mb[2048];
    __shared__ float ssum[64];
    __shared__ float Sb[1024];
    __shared__ float wtmp[32];
    __shared__ int lab[64];

    const int n = blockIdx.x;
    const int tid = threadIdx.x;
    const int wv = tid >> 6;       // 0: alpha, 1: beta
    const int lane = tid & 63;
    const int k = tid & 31;
    const int hw = tid >> 5;       // half-wave id 0..3
    float* drow = Pdiff + (size_t)n * 2048;

    // ---- Phase A: MFMA dots into LDS ----
    {
        const int m16 = lane & 15;     // A-row / W-row within 16-tile
        const int kb = lane >> 4;      // d-block (8 elems)
        const size_t row0 = (size_t)n * 64 + wv * 32;
        const float* arow0 = data + (row0 + m16) * 512 + kb * 8;
        const float* arow1 = arow0 + 16 * 512;
        const float* brow0 = W + (size_t)m16 * 512 + kb * 8;
        const float* brow1 = brow0 + 16 * 512;

        f32x4 acc00 = {0.f, 0.f, 0.f, 0.f}, acc01 = {0.f, 0.f, 0.f, 0.f};
        f32x4 acc10 = {0.f, 0.f, 0.f, 0.f}, acc11 = {0.f, 0.f, 0.f, 0.f};

#pragma unroll 1
        for (int kk = 0; kk < 16; ++kk) {
            const int off = kk * 32;
            float4 a0l = *(const float4*)(arow0 + off);
            float4 a0h = *(const float4*)(arow0 + off + 4);
            float4 a1l = *(const float4*)(arow1 + off);
            float4 a1h = *(const float4*)(arow1 + off + 4);
            float4 b0l = *(const float4*)(brow0 + off);
            float4 b0h = *(const float4*)(brow0 + off + 4);
            float4 b1l = *(const float4*)(brow1 + off);
            float4 b1h = *(const float4*)(brow1 + off + 4);
            bf16x8 a0 = to_bf16x8(a0l, a0h), a1 = to_bf16x8(a1l, a1h);
            bf16x8 b0 = to_bf16x8(b0l, b0h), b1 = to_bf16x8(b1l, b1h);
            acc00 = MFMA16(a0, b0, acc00);
            acc01 = MFMA16(a0, b1, acc01);
            acc10 = MFMA16(a1, b0, acc10);
            acc11 = MFMA16(a1, b1, acc11);
        }
        // C: local row = wv*32 + {0,16} + kb*4 + r, col = {0,16} + m16
        const int ib = wv * 32 + kb * 4;
#pragma unroll
        for (int r = 0; r < 4; ++r) {
            gdb[(ib + r) * 32 + m16]            = acc00[r];
            gdb[(ib + r) * 32 + 16 + m16]       = acc01[r];
            gdb[(ib + 16 + r) * 32 + m16]       = acc10[r];
            gdb[(ib + 16 + r) * 32 + 16 + m16]  = acc11[r];
        }
    }
#pragma unroll
    for (int i = 0; i < 8; ++i) Sb[tid * 8 + i] = 0.f;
    if (tid < 64) lab[tid] = labels[n * 64 + tid];
    __syncthreads();

    // ---- Phase B: gd[i][k] = exp(dots - rowmax); 4 half-waves x 16 rows ----
#pragma unroll
    for (int ii = 0; ii < 16; ++ii) {
        int i = hw * 16 + ii;
        float d = gdb[i * 32 + k];
        float mx = rmax32(d);
        gdb[i * 32 + k] = __expf(d - mx);
    }
    __syncthreads();

    // ---- Phase C: alpha || beta ----
    if (wv == 0) {
        float Ecol[32];
#pragma unroll
        for (int j = 0; j < 32; ++j) Ecol[j] = __expf(Tm[j * 32 + k]);
        float Areg = 1.f;
        for (int i = 0; i < 64; ++i) {
            float t = Areg * gdb[i * 32 + k];
            float un = t * __builtin_amdgcn_rcpf(rsum32(t));
            Unb[i * 32 + k] = un;
            asm volatile("s_waitcnt lgkmcnt(0)" ::: "memory");
            if (i < 63) {
                const float4* uv = (const float4*)(&Unb[i * 32]);
                float a = 0.f;
#pragma unroll
                for (int j8 = 0; j8 < 8; ++j8) {
                    float4 u = uv[j8];
                    a += Ecol[j8 * 4 + 0] * u.x + Ecol[j8 * 4 + 1] * u.y +
                         Ecol[j8 * 4 + 2] * u.z + Ecol[j8 * 4 + 3] * u.w;
                }
                Areg = a;
            }
        }
    } else {
        float Erow[32];
#pragma unroll
        for (int j = 0; j < 32; ++j) Erow[j] = __expf(Tm[k * 32 + j]);
        Mb[63 * 32 + k] = 1.f;
        if (lane == 0) ssum[63] = 32.f;
        float Mreg = 1.f, scur = 32.f;
        for (int i = 63; i > 0; --i) {
            float ww = gdb[i * 32 + k] * Mreg * __builtin_amdgcn_rcpf(scur);
            wtmp[k] = ww;
            asm volatile("s_waitcnt lgkmcnt(0)" ::: "memory");
            const float4* wvv = (const float4*)wtmp;
            float m2 = 0.f;
#pragma unroll
            for (int j8 = 0; j8 < 8; ++j8) {
                float4 u = wvv[j8];
                m2 += Erow[j8 * 4 + 0] * u.x + Erow[j8 * 4 + 1] * u.y +
                      Erow[j8 * 4 + 2] * u.z + Erow[j8 * 4 + 3] * u.w;
            }
            float s2 = rsum32(m2);
            Mb[(i - 1) * 32 + k] = m2;
            if (lane == 0) ssum[i - 1] = s2;
            Mreg = m2; scur = s2;
        }
    }
    __syncthreads();

    // ---- Phase D: p-phase, 4 half-waves x 16 positions ----
    float Scol[32];
#pragma unroll
    for (int j = 0; j < 32; ++j) Scol[j] = 0.f;
    const int i0 = hw * 16;
    for (int ii = 0; ii < 16; ++ii) {
        int i = i0 + ii;
        float un = Unb[i * 32 + k];
        float mm = Mb[i * 32 + k];
        float t = un * mm;
        float Z = rsum32(t);
        float rZ = __builtin_amdgcn_rcpf(Z);
        float pd = ((lab[i] == k) ? 1.f : 0.f) - t * rZ;
        drow[i * 32 + k] = pd;   // Pdiff -> ws for k_dw
        if (i < 63) {
            float q = gdb[(i + 1) * 32 + k] * Mb[(i + 1) * 32 + k] *
                      __builtin_amdgcn_rcpf(ssum[i + 1]);
            float f = q * rZ;
            const float4* uv = (const float4*)(&Unb[i * 32]);
#pragma unroll
            for (int j8 = 0; j8 < 8; ++j8) {
                float4 u = uv[j8];
                Scol[j8 * 4 + 0] += u.x * f; Scol[j8 * 4 + 1] += u.y * f;
                Scol[j8 * 4 + 2] += u.z * f; Scol[j8 * 4 + 3] += u.w * f;
            }
        }
    }
#pragma unroll
    for (int j = 0; j < 32; ++j) atomicAdd(&Sb[j * 32 + k], Scol[j]);
    __syncthreads();

    float* op = dTpart + (size_t)n * 1024;
#pragma unroll
    for (int e = 0; e < 8; ++e) {
        int idx = tid * 8 + e;
        op[idx] = -__expf(Tm[idx]) * Sb[idx];
    }
    __syncthreads();
    if (tid < 63) atomicAdd(&op[lab[tid] * 32 + lab[tid + 1]], 1.0f);
}

// ---------------------------------------------------------------------------
// K3: dw partials = Pdiff^T @ data. grid = 256 word-groups x 4 d-quarters.
// Lane owns float2 of d; wave owns 8 k (uniform Pdiff -> scalar path).
// ---------------------------------------------------------------------------
__global__ __launch_bounds__(256) void k_dw(const float* __restrict__ data,
                                            const float* __restrict__ Pd,
                                            float* __restrict__ dwp) {
    const int g = blockIdx.x >> 2;
    const int q = blockIdx.x & 3;
    const int tid = threadIdx.x;
    const int kg = __builtin_amdgcn_readfirstlane(tid >> 6);
    const int lane = tid & 63;
    const int k0 = kg << 3;
    const int d0 = q * 128 + lane * 2;

    float2 acc[8];
#pragma unroll
    for (int i = 0; i < 8; ++i) acc[i] = make_float2(0.f, 0.f);

    const size_t rbase = (size_t)g * 512;
    const float* dptr = data + rbase * 512 + d0;
    const float4* pptr = (const float4*)(Pd + rbase * 32) + kg * 2;

#define FMA8_2(PA, PB, DV)                                                     \
    acc[0].x += (PA).x * (DV).x; acc[0].y += (PA).x * (DV).y;                  \
    acc[1].x += (PA).y * (DV).x; acc[1].y += (PA).y * (DV).y;                  \
    acc[2].x += (PA).z * (DV).x; acc[2].y += (PA).z * (DV).y;                  \
    acc[3].x += (PA).w * (DV).x; acc[3].y += (PA).w * (DV).y;                  \
    acc[4].x += (PB).x * (DV).x; acc[4].y += (PB).x * (DV).y;                  \
    acc[5].x += (PB).y * (DV).x; acc[5].y += (PB).y * (DV).y;                  \
    acc[6].x += (PB).z * (DV).x; acc[6].y += (PB).z * (DV).y;                  \
    acc[7].x += (PB).w * (DV).x; acc[7].y += (PB).w * (DV).y;

    for (int r = 0; r < 512; r += 4) {
        float2 dv0 = *(const float2*)(dptr + (size_t)(r + 0) * 512);
        float2 dv1 = *(const float2*)(dptr + (size_t)(r + 1) * 512);
        float2 dv2 = *(const float2*)(dptr + (size_t)(r + 2) * 512);
        float2 dv3 = *(const float2*)(dptr + (size_t)(r + 3) * 512);
        float4 pa0 = pptr[(r + 0) * 8], pb0 = pptr[(r + 0) * 8 + 1];
        float4 pa1 = pptr[(r + 1) * 8], pb1 = pptr[(r + 1) * 8 + 1];
        float4 pa2 = pptr[(r + 2) * 8], pb2 = pptr[(r + 2) * 8 + 1];
        float4 pa3 = pptr[(r + 3) * 8], pb3 = pptr[(r + 3) * 8 + 1];
        FMA8_2(pa0, pb0, dv0)
        FMA8_2(pa1, pb1, dv1)
        FMA8_2(pa2, pb2, dv2)
        FMA8_2(pa3, pb3, dv3)
    }
#undef FMA8_2

    float* op = dwp + (size_t)g * 16384;
#pragma unroll
    for (int kk = 0; kk < 8; ++kk)
        *(float2*)(op + (k0 + kk) * 512 + d0) = acc[kk];
}

// ---------------------------------------------------------------------------
// K4: reduce partials, scale 1/N. blocks 0..255: dw; 256..319: dT.
// ---------------------------------------------------------------------------
__global__ __launch_bounds__(256) void k_final(const float* __restrict__ dwp,
                                               const float* __restrict__ dTp,
                                               float* __restrict__ out) {
    __shared__ float red[256];
    const int b = blockIdx.x, t = threadIdx.x;
    const float inv = 1.0f / 2048.0f;
    if (b < 256) {
        const int q = t >> 6, ol = t & 63;
        const int oi = b * 64 + ol;
        float s = 0.f;
#pragma unroll 4
        for (int j = 0; j < 64; ++j) s += dwp[(size_t)(q * 64 + j) * 16384 + oi];
        red[t] = s;
        __syncthreads();
        if (t < 64) out[b * 64 + t] = (red[t] + red[t + 64] + red[t + 128] + red[t + 192]) * inv;
    } else {
        const int ol = t >> 4, q = t & 15;
        const int oi = (b - 256) * 16 + ol;
        float s = 0.f;
#pragma unroll 4
        for (int j = 0; j < 128; ++j) s += dTp[(size_t)(q * 128 + j) * 1024 + oi];
        s += __shfl_xor(s, 1, 16); s += __shfl_xor(s, 2, 16);
        s += __shfl_xor(s, 4, 16); s += __shfl_xor(s, 8, 16);
        if (q == 0) out[16384 + oi] = s * inv;
    }
}

// ---------------------------------------------------------------------------
// ws layout (floats): [0,4194304) Pdiff | [4194304,6291456) dT partials
//                     [6291456,10485760) dw partials   (~42 MB total)
// ---------------------------------------------------------------------------
extern "C" void kernel_launch(void* const* d_in, const int* in_sizes, int n_in,
                              void* d_out, int out_size, void* d_ws, size_t ws_size,
                              hipStream_t stream) {
    const float* W = (const float*)d_in[0];
    const float* Tm = (const float*)d_in[1];
    const float* data = (const float*)d_in[2];
    const int* labels = (const int*)d_in[3];
    float* out = (float*)d_out;
    float* ws = (float*)d_ws;

    float* Pdiff = ws;                 // 2048*64*32
    float* dTpart = ws + 4194304;      // 2048*1024
    float* dwpart = ws + 6291456;      // 256*16384

    hipLaunchKernelGGL(k_word, dim3(2048), dim3(128), 0, stream,
                       data, W, Tm, labels, Pdiff, dTpart);
    hipLaunchKernelGGL(k_dw, dim3(1024), dim3(256), 0, stream, data, Pdiff, dwpart);
    hipLaunchKernelGGL(k_final, dim3(320), dim3(256), 0, stream, dwpart, dTpart, out);
}